// Round 4
// baseline (3101.437 us; speedup 1.0000x reference)
//
#include <hip/hip_runtime.h>
#include <hip/hip_bf16.h>
#include <math.h>

// ============================================================================
// LSTMPolicy: encoder -> masked 2-layer LSTM -> actor/critic heads
// B=512 S=512 OBS=64 H=128 A=9 L=2
//
// ROUND-3 FIX: d_out is FLOAT32 (reference returns f32; round-2 absmax=20.4
// matched log_prob bytes aliasing into the f32 action region when written
// as bf16). All outputs now written as f32. Internal pipeline stays bf16.
// ============================================================================

#define DEV __device__ __forceinline__

typedef __attribute__((ext_vector_type(4))) float f4;
typedef __attribute__((ext_vector_type(8))) short s16x8;

static constexpr int Bsz = 512, Ssz = 512, OBSD = 64, HD = 128, AD = 9;
static constexpr int TOK = Bsz * Ssz;                       // 262144

// d_out offsets (f32 elements)
static constexpr size_t LP_OFF  = (size_t)TOK * AD;         // 2359296
static constexpr size_t VAL_OFF = LP_OFF + TOK;             // 2621440
static constexpr size_t H_OFF   = VAL_OFF + TOK;            // 2883584
static constexpr size_t C_OFF   = H_OFF + 2 * Bsz * HD;     // 3014656

// ws offsets (bytes)
static constexpr size_t WS_SEQ   = 0;                       // bf16 (B*S,128): enc, then lstm_out in-place
static constexpr size_t WS_WIH1B = (size_t)TOK * HD * 2;    // 67108864
static constexpr size_t WS_AMW1B = WS_WIH1B + 512 * 128 * 2;
static constexpr size_t WS_AMW2P = WS_AMW1B + 64 * 128 * 2;
static constexpr size_t WS_CRW1B = WS_AMW2P + 16 * 64 * 2;
static constexpr size_t WS_CRW2P = WS_CRW1B + 64 * 128 * 2;

DEV unsigned short f2bf(float f) {
  union { float f; unsigned u; } v; v.f = f;
  unsigned r = v.u + 0x7fffu + ((v.u >> 16) & 1u);
  return (unsigned short)(r >> 16);
}
DEV s16x8 cvt8(f4 a, f4 b) {
  s16x8 r;
  r[0]=(short)f2bf(a[0]); r[1]=(short)f2bf(a[1]); r[2]=(short)f2bf(a[2]); r[3]=(short)f2bf(a[3]);
  r[4]=(short)f2bf(b[0]); r[5]=(short)f2bf(b[1]); r[6]=(short)f2bf(b[2]); r[7]=(short)f2bf(b[3]);
  return r;
}
DEV f4 splat4(float v) { f4 r = {v, v, v, v}; return r; }
DEV f4 mfma16(s16x8 a, s16x8 b, f4 c) {
  return __builtin_amdgcn_mfma_f32_16x16x32_bf16(a, b, c, 0, 0, 0);
}
DEV float fexp2(float x) { return __builtin_amdgcn_exp2f(x); }
DEV float frcp(float x)  { return __builtin_amdgcn_rcpf(x); }
DEV float sigm(float x)   { return frcp(1.f + fexp2(-1.4426950408889634f * x)); }
DEV float tanh_f(float x) { return 2.f * frcp(1.f + fexp2(-2.8853900817779268f * x)) - 1.f; }

// ---------------------------------------------------------------------------
// k_prep: one-time f32->bf16 weight conversions (wih1 stream + head weights)
// ---------------------------------------------------------------------------
__global__ void k_prep(const float* __restrict__ wih1, const float* __restrict__ amw1,
                       const float* __restrict__ amw2, const float* __restrict__ crw1,
                       const float* __restrict__ crw2,
                       unsigned short* __restrict__ wih1b, unsigned short* __restrict__ amw1b,
                       unsigned short* __restrict__ amw2p, unsigned short* __restrict__ crw1b,
                       unsigned short* __restrict__ crw2p)
{
  int i = blockIdx.x * 256 + threadIdx.x;
  if (i < 65536) wih1b[i] = f2bf(wih1[i]);
  if (i < 8192) { amw1b[i] = f2bf(amw1[i]); crw1b[i] = f2bf(crw1[i]); }
  if (i < 1024) {
    int n = i >> 6, k = i & 63;
    amw2p[i] = (n < 9) ? f2bf(amw2[n * 64 + k]) : (unsigned short)0;
    crw2p[i] = (n == 0) ? f2bf(crw2[k]) : (unsigned short)0;
  }
}

// ---------------------------------------------------------------------------
// k_encoder: per 16-token wave: obs @ w1^T -> LN -> relu -> @ w2^T -> relu
// ---------------------------------------------------------------------------
__global__ __launch_bounds__(256) void k_encoder(
    const float* __restrict__ obs,
    const float* __restrict__ w1, const float* __restrict__ b1,
    const float* __restrict__ lng, const float* __restrict__ lnb,
    const float* __restrict__ w2, const float* __restrict__ b2,
    unsigned short* __restrict__ enc)
{
  __shared__ unsigned short sy[4][2048];   // per-wave 16x128 bf16 tile (swizzled)
  const int tid = threadIdx.x, lane = tid & 63, wv = tid >> 6;
  const int cl = lane & 15, grp = lane >> 4;
  const size_t tok0 = ((size_t)blockIdx.x * 4 + wv) * 16;

  s16x8 aob[2];
  {
    const float* p = obs + (tok0 + cl) * 64 + grp * 8;
    aob[0] = cvt8(*(const f4*)p, *(const f4*)(p + 4));
    aob[1] = cvt8(*(const f4*)(p + 32), *(const f4*)(p + 36));
  }

  f4 acc[8];
#pragma unroll
  for (int n = 0; n < 8; ++n) acc[n] = splat4(0.f);
#pragma unroll
  for (int kk = 0; kk < 2; ++kk)
#pragma unroll
    for (int n = 0; n < 8; ++n) {
      const float* p = w1 + (size_t)(n * 16 + cl) * 64 + kk * 32 + grp * 8;
      acc[n] = mfma16(aob[kk], cvt8(*(const f4*)p, *(const f4*)(p + 4)), acc[n]);
    }

  float y[8][4], s[4] = {0,0,0,0}, q[4] = {0,0,0,0};
#pragma unroll
  for (int n = 0; n < 8; ++n) {
    float bb = b1[n * 16 + cl];
#pragma unroll
    for (int i = 0; i < 4; ++i) { float v = acc[n][i] + bb; y[n][i] = v; s[i] += v; q[i] += v * v; }
  }
#pragma unroll
  for (int i = 0; i < 4; ++i)
    for (int m = 1; m < 16; m <<= 1) { s[i] += __shfl_xor(s[i], m); q[i] += __shfl_xor(q[i], m); }
  float mean[4], rstd[4];
#pragma unroll
  for (int i = 0; i < 4; ++i) {
    mean[i] = s[i] * (1.f / 128.f);
    float var = q[i] * (1.f / 128.f) - mean[i] * mean[i];
    rstd[i] = rsqrtf(var + 1e-5f);
  }
  unsigned short* my = sy[wv];
#pragma unroll
  for (int n = 0; n < 8; ++n) {
    float gg = lng[n * 16 + cl], bb = lnb[n * 16 + cl];
#pragma unroll
    for (int i = 0; i < 4; ++i) {
      float v = (y[n][i] - mean[i]) * rstd[i] * gg + bb;
      v = v > 0.f ? v : 0.f;
      int row = grp * 4 + i;
      *(unsigned short*)((char*)my + row * 256 + (((n * 16 + cl) * 2) ^ ((row & 7) << 4))) = f2bf(v);
    }
  }
  __syncthreads();

  f4 acc2[8];
#pragma unroll
  for (int n = 0; n < 8; ++n) acc2[n] = splat4(0.f);
#pragma unroll
  for (int kk = 0; kk < 4; ++kk) {
    s16x8 a2 = *(const s16x8*)((char*)my + cl * 256 + ((kk * 64 + grp * 16) ^ ((cl & 7) << 4)));
#pragma unroll
    for (int n = 0; n < 8; ++n) {
      const float* p = w2 + (size_t)(n * 16 + cl) * 128 + kk * 32 + grp * 8;
      acc2[n] = mfma16(a2, cvt8(*(const f4*)p, *(const f4*)(p + 4)), acc2[n]);
    }
  }
#pragma unroll
  for (int n = 0; n < 8; ++n) {
    float bb = b2[n * 16 + cl];
#pragma unroll
    for (int i = 0; i < 4; ++i) {
      float v = acc2[n][i] + bb; v = v > 0.f ? v : 0.f;
      enc[(tok0 + grp * 4 + i) * 128 + n * 16 + cl] = f2bf(v);
    }
  }
}

// ---------------------------------------------------------------------------
// k_lstm: 32 blocks x 16 batch rows, 8 waves (each owns 16 units x 4 gates),
// sequential over 512 steps. wih0 in LDS, whh0/whh1 in VGPR frags, wih1
// streamed from L2 (bf16). h exchanged via swizzled 16x128 LDS tiles.
// ---------------------------------------------------------------------------
__global__ __launch_bounds__(512, 2) void k_lstm(
    const unsigned short* enc_in,      // aliases lstm_out (in-place, safe per-step)
    unsigned short* lstm_out,
    const float* __restrict__ masks,
    const float* __restrict__ wih0f, const float* __restrict__ whh0f,
    const float* __restrict__ bih0, const float* __restrict__ bhh0,
    const unsigned short* __restrict__ wih1b, const float* __restrict__ whh1f,
    const float* __restrict__ bih1, const float* __restrict__ bhh1,
    float* __restrict__ out_h, float* __restrict__ out_c)
{
  extern __shared__ char sm[];
  char* s_h0 = sm + 131072;                                 // [16][128] bf16 swizzled
  char* s_h1 = sm + 135168;
  unsigned short* s_mk = (unsigned short*)(sm + 139264);    // [512][16] flags

  const int tid = threadIdx.x, lane = tid & 63, wv = tid >> 6;
  const int cl = lane & 15, grp = lane >> 4;
  const int b0 = blockIdx.x * 16, u0 = wv * 16;
  const s16x8 z8 = {0,0,0,0,0,0,0,0};

  // ---- one-time staging ----
  for (int idx = tid; idx < 8192; idx += 512) {             // wih0 -> swizzled LDS bf16
    int row = idx >> 4, c8 = idx & 15;
    const float* p = wih0f + (size_t)row * 128 + c8 * 8;
    s16x8 v = cvt8(*(const f4*)p, *(const f4*)(p + 4));
    *(s16x8*)(sm + row * 256 + ((c8 * 16) ^ ((row & 7) << 4))) = v;
  }
  for (int idx = tid; idx < 2048; idx += 512) { ((unsigned short*)s_h0)[idx] = 0; ((unsigned short*)s_h1)[idx] = 0; }
  for (int idx = tid; idx < 8192; idx += 512) {
    int t = idx >> 4, r = idx & 15;
    s_mk[idx] = (masks[(size_t)(b0 + r) * 512 + t] != 0.f) ? 1u : 0u;
  }

  s16x8 Bh0[4][4], Bh1[4][4];
#pragma unroll
  for (int g = 0; g < 4; ++g)
#pragma unroll
    for (int kk = 0; kk < 4; ++kk) {
      const float* p0 = whh0f + (size_t)(g * 128 + u0 + cl) * 128 + kk * 32 + grp * 8;
      Bh0[g][kk] = cvt8(*(const f4*)p0, *(const f4*)(p0 + 4));
      const float* p1 = whh1f + (size_t)(g * 128 + u0 + cl) * 128 + kk * 32 + grp * 8;
      Bh1[g][kk] = cvt8(*(const f4*)p1, *(const f4*)(p1 + 4));
    }
  float bias0[4], bias1[4];
#pragma unroll
  for (int g = 0; g < 4; ++g) {
    bias0[g] = bih0[g * 128 + u0 + cl] + bhh0[g * 128 + u0 + cl];
    bias1[g] = bih1[g * 128 + u0 + cl] + bhh1[g * 128 + u0 + cl];
  }
  float c0[4] = {0,0,0,0}, c1[4] = {0,0,0,0};
  float h0r[4] = {0,0,0,0}, h1r[4] = {0,0,0,0};

  const int swz = (cl & 7) << 4;
  int hoff[4];
#pragma unroll
  for (int kk = 0; kk < 4; ++kk) hoff[kk] = cl * 256 + ((kk * 64 + grp * 16) ^ swz);
  const char* w0l = sm + (u0 + cl) * 256;                          // + g*32768 + koff
  const unsigned short* encl = enc_in + (size_t)(b0 + cl) * 65536 + grp * 8;
  const unsigned short* w1l = wih1b + (size_t)(u0 + cl) * 128 + grp * 8;  // + g*16384 + kk*32

  __syncthreads();

  for (int t = 0; t < 512; ++t) {
    const int mA = s_mk[t * 16 + cl];
    float mc[4];
#pragma unroll
    for (int i = 0; i < 4; ++i) mc[i] = s_mk[t * 16 + grp * 4 + i] ? 1.f : 0.f;

    // ---------- layer 0: gates = enc@wih0^T + (m*h0)@whh0^T + bias ----------
    f4 acc[4];
#pragma unroll
    for (int g = 0; g < 4; ++g) acc[g] = splat4(bias0[g]);
#pragma unroll
    for (int kk = 0; kk < 4; ++kk) {
      s16x8 ax = *(const s16x8*)(encl + (size_t)t * 128 + kk * 32);
      s16x8 ah = *(const s16x8*)(s_h0 + hoff[kk]);
      if (!mA) ah = z8;
#pragma unroll
      for (int g = 0; g < 4; ++g) {
        s16x8 bw = *(const s16x8*)(w0l + g * 32768 + ((kk * 64 + grp * 16) ^ swz));
        acc[g] = mfma16(ax, bw, acc[g]);
        acc[g] = mfma16(ah, Bh0[g][kk], acc[g]);
      }
    }
#pragma unroll
    for (int i = 0; i < 4; ++i) {
      float ig = sigm(acc[0][i]), fg = sigm(acc[1][i]);
      float gg = tanh_f(acc[2][i]), og = sigm(acc[3][i]);
      float c = fg * (c0[i] * mc[i]) + ig * gg;
      c0[i] = c; h0r[i] = og * tanh_f(c);
    }
    __syncthreads();               // all waves done reading s_h0(t-1)
#pragma unroll
    for (int i = 0; i < 4; ++i) {
      int row = grp * 4 + i;
      *(unsigned short*)(s_h0 + row * 256 + (((u0 + cl) * 2) ^ ((row & 7) << 4))) = f2bf(h0r[i]);
    }
    __syncthreads();               // h0(t) visible

    // ---------- layer 1: gates = h0@wih1^T + (m*h1)@whh1^T + bias ----------
#pragma unroll
    for (int g = 0; g < 4; ++g) acc[g] = splat4(bias1[g]);
    s16x8 ax1[4], ah1[4];
#pragma unroll
    for (int kk = 0; kk < 4; ++kk) {
      ax1[kk] = *(const s16x8*)(s_h0 + hoff[kk]);
      ah1[kk] = *(const s16x8*)(s_h1 + hoff[kk]);
      if (!mA) ah1[kk] = z8;
    }
#pragma unroll
    for (int g = 0; g < 4; ++g) {
#pragma unroll
      for (int kk = 0; kk < 4; ++kk) {
        s16x8 bx = *(const s16x8*)(w1l + g * 16384 + kk * 32);   // L2-resident stream
        acc[g] = mfma16(ax1[kk], bx, acc[g]);
        acc[g] = mfma16(ah1[kk], Bh1[g][kk], acc[g]);
      }
    }
#pragma unroll
    for (int i = 0; i < 4; ++i) {
      float ig = sigm(acc[0][i]), fg = sigm(acc[1][i]);
      float gg = tanh_f(acc[2][i]), og = sigm(acc[3][i]);
      float c = fg * (c1[i] * mc[i]) + ig * gg;
      c1[i] = c; h1r[i] = og * tanh_f(c);
    }
    __syncthreads();               // readers of s_h1(t-1) done
#pragma unroll
    for (int i = 0; i < 4; ++i) {
      int row = grp * 4 + i;
      unsigned short hb = f2bf(h1r[i]);
      *(unsigned short*)(s_h1 + row * 256 + (((u0 + cl) * 2) ^ ((row & 7) << 4))) = hb;
      lstm_out[(size_t)(b0 + row) * 65536 + (size_t)t * 128 + u0 + cl] = hb;
    }
    __syncthreads();               // h1(t) visible for t+1
  }

#pragma unroll
  for (int i = 0; i < 4; ++i) {
    size_t b = (size_t)b0 + grp * 4 + i;
    out_h[b * 128 + u0 + cl]         = h0r[i];
    out_h[65536 + b * 128 + u0 + cl] = h1r[i];
    out_c[b * 128 + u0 + cl]         = c0[i];
    out_c[65536 + b * 128 + u0 + cl] = c1[i];
  }
}

// ---------------------------------------------------------------------------
// k_heads: actor mean->action/log_prob + critic value, per 16-token wave
// ---------------------------------------------------------------------------
__global__ __launch_bounds__(256) void k_heads(
    const unsigned short* __restrict__ lo,
    const float* __restrict__ noise,
    const unsigned short* __restrict__ amw1b, const float* __restrict__ am_b1,
    const unsigned short* __restrict__ amw2p, const float* __restrict__ am_b2,
    const float* __restrict__ log_std,
    const unsigned short* __restrict__ crw1b, const float* __restrict__ cr_b1,
    const unsigned short* __restrict__ crw2p, const float* __restrict__ cr_b2,
    float* __restrict__ out)
{
  __shared__ unsigned short sha[4][1024];
  __shared__ unsigned short shc[4][1024];
  const int tid = threadIdx.x, lane = tid & 63, wv = tid >> 6;
  const int cl = lane & 15, grp = lane >> 4;
  const size_t tok0 = ((size_t)blockIdx.x * 4 + wv) * 16;

  s16x8 a[4];
  {
    const unsigned short* p = lo + (tok0 + cl) * 128 + grp * 8;
#pragma unroll
    for (int kk = 0; kk < 4; ++kk) a[kk] = *(const s16x8*)(p + kk * 32);
  }

  f4 acc[4], accc[4];
#pragma unroll
  for (int n = 0; n < 4; ++n) { acc[n] = splat4(0.f); accc[n] = splat4(0.f); }
#pragma unroll
  for (int kk = 0; kk < 4; ++kk)
#pragma unroll
    for (int n = 0; n < 4; ++n) {
      acc[n]  = mfma16(a[kk], *(const s16x8*)(amw1b + (size_t)(n * 16 + cl) * 128 + kk * 32 + grp * 8), acc[n]);
      accc[n] = mfma16(a[kk], *(const s16x8*)(crw1b + (size_t)(n * 16 + cl) * 128 + kk * 32 + grp * 8), accc[n]);
    }
#pragma unroll
  for (int n = 0; n < 4; ++n) {
    float ba = am_b1[n * 16 + cl], bc = cr_b1[n * 16 + cl];
#pragma unroll
    for (int i = 0; i < 4; ++i) {
      int row = grp * 4 + i;
      int off = row * 128 + (((n * 16 + cl) * 2) ^ ((row & 7) << 4));
      float va = acc[n][i] + ba;  va = va > 0.f ? va : 0.f;
      float vc = accc[n][i] + bc; vc = vc > 0.f ? vc : 0.f;
      *(unsigned short*)((char*)sha[wv] + off) = f2bf(va);
      *(unsigned short*)((char*)shc[wv] + off) = f2bf(vc);
    }
  }
  __syncthreads();

  f4 am = splat4(0.f), vv = splat4(0.f);
#pragma unroll
  for (int kk = 0; kk < 2; ++kk) {
    int off = cl * 128 + ((kk * 64 + grp * 16) ^ ((cl & 7) << 4));
    s16x8 a2 = *(const s16x8*)((char*)sha[wv] + off);
    s16x8 c2 = *(const s16x8*)((char*)shc[wv] + off);
    am = mfma16(a2, *(const s16x8*)(amw2p + (size_t)cl * 64 + kk * 32 + grp * 8), am);
    vv = mfma16(c2, *(const s16x8*)(crw2p + (size_t)cl * 64 + kk * 32 + grp * 8), vv);
  }

  float ls = 0.f, stdv = 0.f, b2a = 0.f;
  if (cl < 9) {
    float l = log_std[cl];
    ls = fminf(fmaxf(l, -4.f), 0.f);
    stdv = fexp2(ls * 1.4426950408889634f);
    b2a = am_b2[cl];
  }
  float crb2 = cr_b2[0];
#pragma unroll
  for (int i = 0; i < 4; ++i) {
    size_t tok = tok0 + grp * 4 + i;
    float lp = 0.f;
    if (cl < 9) {
      float meanv = tanh_f(am[i] + b2a);
      float nz = noise[tok * 9 + cl];
      float act = meanv + stdv * nz;
      float z = (act - meanv) / stdv;
      lp = -0.5f * z * z - ls - 0.91893853320467274f;
      out[tok * 9 + cl] = act;
    }
#pragma unroll
    for (int m = 1; m < 16; m <<= 1) lp += __shfl_xor(lp, m);
    if (cl == 0) {
      out[LP_OFF + tok]  = lp;
      out[VAL_OFF + tok] = vv[i] + crb2;
    }
  }
}

// ---------------------------------------------------------------------------
extern "C" void kernel_launch(void* const* d_in, const int* in_sizes, int n_in,
                              void* d_out, int out_size, void* d_ws, size_t ws_size,
                              hipStream_t stream)
{
  const float* obs     = (const float*)d_in[0];
  const float* masks   = (const float*)d_in[1];
  const float* noise   = (const float*)d_in[2];
  const float* enc_w1  = (const float*)d_in[3];
  const float* enc_b1  = (const float*)d_in[4];
  const float* ln_g    = (const float*)d_in[5];
  const float* ln_b    = (const float*)d_in[6];
  const float* enc_w2  = (const float*)d_in[7];
  const float* enc_b2  = (const float*)d_in[8];
  const float* wih0    = (const float*)d_in[9];
  const float* whh0    = (const float*)d_in[10];
  const float* bih0    = (const float*)d_in[11];
  const float* bhh0    = (const float*)d_in[12];
  const float* wih1    = (const float*)d_in[13];
  const float* whh1    = (const float*)d_in[14];
  const float* bih1    = (const float*)d_in[15];
  const float* bhh1    = (const float*)d_in[16];
  const float* am_w1   = (const float*)d_in[17];
  const float* am_b1   = (const float*)d_in[18];
  const float* am_w2   = (const float*)d_in[19];
  const float* am_b2   = (const float*)d_in[20];
  const float* log_std = (const float*)d_in[21];
  const float* cr_w1   = (const float*)d_in[22];
  const float* cr_b1   = (const float*)d_in[23];
  const float* cr_w2   = (const float*)d_in[24];
  const float* cr_b2   = (const float*)d_in[25];

  char* ws = (char*)d_ws;
  unsigned short* seq   = (unsigned short*)(ws + WS_SEQ);
  unsigned short* wih1b = (unsigned short*)(ws + WS_WIH1B);
  unsigned short* amw1b = (unsigned short*)(ws + WS_AMW1B);
  unsigned short* amw2p = (unsigned short*)(ws + WS_AMW2P);
  unsigned short* crw1b = (unsigned short*)(ws + WS_CRW1B);
  unsigned short* crw2p = (unsigned short*)(ws + WS_CRW2P);
  float* out            = (float*)d_out;

  hipFuncSetAttribute((const void*)k_lstm, hipFuncAttributeMaxDynamicSharedMemorySize, 155648);

  k_prep<<<256, 256, 0, stream>>>(wih1, am_w1, am_w2, cr_w1, cr_w2,
                                  wih1b, amw1b, amw2p, crw1b, crw2p);
  k_encoder<<<4096, 256, 0, stream>>>(obs, enc_w1, enc_b1, ln_g, ln_b, enc_w2, enc_b2, seq);
  k_lstm<<<32, 512, 155648, stream>>>(seq, seq, masks, wih0, whh0, bih0, bhh0,
                                      wih1b, whh1, bih1, bhh1, out + H_OFF, out + C_OFF);
  k_heads<<<4096, 256, 0, stream>>>(seq, noise, amw1b, am_b1, amw2p, am_b2, log_std,
                                    crw1b, cr_b1, crw2p, cr_b2, out);
}

// Round 7
// 2659.083 us; speedup vs baseline: 1.1664x; 1.1664x over previous
//
#include <hip/hip_runtime.h>
#include <hip/hip_bf16.h>
#include <math.h>

// ============================================================================
// LSTMPolicy: encoder -> masked 2-layer LSTM -> actor/critic heads
// B=512 S=512 OBS=64 H=128 A=9 L=2
//
// ROUND-5: k_lstm latency rewrite (was 12.7k cy/step, all pipes idle):
//  - enc(t+1) register prefetch (hide ~900cy HBM)
//  - wih1 loads issued mid-layer0 (hide ~250cy L2)
//  - double-buffered h tiles: 2 barriers/step (was 4)
//  - coalesced lstm_out stores from LDS (8B/thread, was 4x2B scattered/lane)
//  - masks as 16-bit bitmap per step (2KB LDS)
// encoder / heads / prep unchanged (passed round 4, absmax 0.0625).
// ============================================================================

#define DEV __device__ __forceinline__

typedef __attribute__((ext_vector_type(4))) float f4;
typedef __attribute__((ext_vector_type(8))) short s16x8;

static constexpr int Bsz = 512, Ssz = 512, OBSD = 64, HD = 128, AD = 9;
static constexpr int TOK = Bsz * Ssz;                       // 262144

// d_out offsets (f32 elements)
static constexpr size_t LP_OFF  = (size_t)TOK * AD;         // 2359296
static constexpr size_t VAL_OFF = LP_OFF + TOK;             // 2621440
static constexpr size_t H_OFF   = VAL_OFF + TOK;            // 2883584
static constexpr size_t C_OFF   = H_OFF + 2 * Bsz * HD;     // 3014656

// ws offsets (bytes)
static constexpr size_t WS_SEQ   = 0;                       // bf16 (B*S,128): enc, then lstm_out in-place
static constexpr size_t WS_WIH1B = (size_t)TOK * HD * 2;    // 67108864
static constexpr size_t WS_AMW1B = WS_WIH1B + 512 * 128 * 2;
static constexpr size_t WS_AMW2P = WS_AMW1B + 64 * 128 * 2;
static constexpr size_t WS_CRW1B = WS_AMW2P + 16 * 64 * 2;
static constexpr size_t WS_CRW2P = WS_CRW1B + 64 * 128 * 2;

// k_lstm LDS layout (bytes)
static constexpr int L_H0  = 131072;   // 2 x [16][128] bf16 swizzled (parity)
static constexpr int L_H1  = 139264;   // 2 x [16][128] bf16 swizzled (parity)
static constexpr int L_MKB = 147456;   // 512 x u32 mask bitmaps
static constexpr int L_TOT = 149504;

DEV unsigned short f2bf(float f) {
  union { float f; unsigned u; } v; v.f = f;
  unsigned r = v.u + 0x7fffu + ((v.u >> 16) & 1u);
  return (unsigned short)(r >> 16);
}
DEV s16x8 cvt8(f4 a, f4 b) {
  s16x8 r;
  r[0]=(short)f2bf(a[0]); r[1]=(short)f2bf(a[1]); r[2]=(short)f2bf(a[2]); r[3]=(short)f2bf(a[3]);
  r[4]=(short)f2bf(b[0]); r[5]=(short)f2bf(b[1]); r[6]=(short)f2bf(b[2]); r[7]=(short)f2bf(b[3]);
  return r;
}
DEV f4 splat4(float v) { f4 r = {v, v, v, v}; return r; }
DEV f4 mfma16(s16x8 a, s16x8 b, f4 c) {
  return __builtin_amdgcn_mfma_f32_16x16x32_bf16(a, b, c, 0, 0, 0);
}
DEV float fexp2(float x) { return __builtin_amdgcn_exp2f(x); }
DEV float frcp(float x)  { return __builtin_amdgcn_rcpf(x); }
DEV float sigm(float x)   { return frcp(1.f + fexp2(-1.4426950408889634f * x)); }
DEV float tanh_f(float x) { return 2.f * frcp(1.f + fexp2(-2.8853900817779268f * x)) - 1.f; }

// ---------------------------------------------------------------------------
// k_prep: one-time f32->bf16 weight conversions (wih1 stream + head weights)
// ---------------------------------------------------------------------------
__global__ void k_prep(const float* __restrict__ wih1, const float* __restrict__ amw1,
                       const float* __restrict__ amw2, const float* __restrict__ crw1,
                       const float* __restrict__ crw2,
                       unsigned short* __restrict__ wih1b, unsigned short* __restrict__ amw1b,
                       unsigned short* __restrict__ amw2p, unsigned short* __restrict__ crw1b,
                       unsigned short* __restrict__ crw2p)
{
  int i = blockIdx.x * 256 + threadIdx.x;
  if (i < 65536) wih1b[i] = f2bf(wih1[i]);
  if (i < 8192) { amw1b[i] = f2bf(amw1[i]); crw1b[i] = f2bf(crw1[i]); }
  if (i < 1024) {
    int n = i >> 6, k = i & 63;
    amw2p[i] = (n < 9) ? f2bf(amw2[n * 64 + k]) : (unsigned short)0;
    crw2p[i] = (n == 0) ? f2bf(crw2[k]) : (unsigned short)0;
  }
}

// ---------------------------------------------------------------------------
// k_encoder: per 16-token wave: obs @ w1^T -> LN -> relu -> @ w2^T -> relu
// ---------------------------------------------------------------------------
__global__ __launch_bounds__(256) void k_encoder(
    const float* __restrict__ obs,
    const float* __restrict__ w1, const float* __restrict__ b1,
    const float* __restrict__ lng, const float* __restrict__ lnb,
    const float* __restrict__ w2, const float* __restrict__ b2,
    unsigned short* __restrict__ enc)
{
  __shared__ unsigned short sy[4][2048];   // per-wave 16x128 bf16 tile (swizzled)
  const int tid = threadIdx.x, lane = tid & 63, wv = tid >> 6;
  const int cl = lane & 15, grp = lane >> 4;
  const size_t tok0 = ((size_t)blockIdx.x * 4 + wv) * 16;

  s16x8 aob[2];
  {
    const float* p = obs + (tok0 + cl) * 64 + grp * 8;
    aob[0] = cvt8(*(const f4*)p, *(const f4*)(p + 4));
    aob[1] = cvt8(*(const f4*)(p + 32), *(const f4*)(p + 36));
  }

  f4 acc[8];
#pragma unroll
  for (int n = 0; n < 8; ++n) acc[n] = splat4(0.f);
#pragma unroll
  for (int kk = 0; kk < 2; ++kk)
#pragma unroll
    for (int n = 0; n < 8; ++n) {
      const float* p = w1 + (size_t)(n * 16 + cl) * 64 + kk * 32 + grp * 8;
      acc[n] = mfma16(aob[kk], cvt8(*(const f4*)p, *(const f4*)(p + 4)), acc[n]);
    }

  float y[8][4], s[4] = {0,0,0,0}, q[4] = {0,0,0,0};
#pragma unroll
  for (int n = 0; n < 8; ++n) {
    float bb = b1[n * 16 + cl];
#pragma unroll
    for (int i = 0; i < 4; ++i) { float v = acc[n][i] + bb; y[n][i] = v; s[i] += v; q[i] += v * v; }
  }
#pragma unroll
  for (int i = 0; i < 4; ++i)
    for (int m = 1; m < 16; m <<= 1) { s[i] += __shfl_xor(s[i], m); q[i] += __shfl_xor(q[i], m); }
  float mean[4], rstd[4];
#pragma unroll
  for (int i = 0; i < 4; ++i) {
    mean[i] = s[i] * (1.f / 128.f);
    float var = q[i] * (1.f / 128.f) - mean[i] * mean[i];
    rstd[i] = rsqrtf(var + 1e-5f);
  }
  unsigned short* my = sy[wv];
#pragma unroll
  for (int n = 0; n < 8; ++n) {
    float gg = lng[n * 16 + cl], bb = lnb[n * 16 + cl];
#pragma unroll
    for (int i = 0; i < 4; ++i) {
      float v = (y[n][i] - mean[i]) * rstd[i] * gg + bb;
      v = v > 0.f ? v : 0.f;
      int row = grp * 4 + i;
      *(unsigned short*)((char*)my + row * 256 + (((n * 16 + cl) * 2) ^ ((row & 7) << 4))) = f2bf(v);
    }
  }
  __syncthreads();

  f4 acc2[8];
#pragma unroll
  for (int n = 0; n < 8; ++n) acc2[n] = splat4(0.f);
#pragma unroll
  for (int kk = 0; kk < 4; ++kk) {
    s16x8 a2 = *(const s16x8*)((char*)my + cl * 256 + ((kk * 64 + grp * 16) ^ ((cl & 7) << 4)));
#pragma unroll
    for (int n = 0; n < 8; ++n) {
      const float* p = w2 + (size_t)(n * 16 + cl) * 128 + kk * 32 + grp * 8;
      acc2[n] = mfma16(a2, cvt8(*(const f4*)p, *(const f4*)(p + 4)), acc2[n]);
    }
  }
#pragma unroll
  for (int n = 0; n < 8; ++n) {
    float bb = b2[n * 16 + cl];
#pragma unroll
    for (int i = 0; i < 4; ++i) {
      float v = acc2[n][i] + bb; v = v > 0.f ? v : 0.f;
      enc[(tok0 + grp * 4 + i) * 128 + n * 16 + cl] = f2bf(v);
    }
  }
}

// ---------------------------------------------------------------------------
// k_lstm: 32 blocks x 16 batch rows, 8 waves (each owns 16 units x 4 gates),
// sequential over 512 steps. wih0 in LDS, whh0/whh1 in VGPR frags, wih1
// streamed from L2 (issued mid-layer0). enc prefetched one step ahead.
// h tiles double-buffered -> 2 barriers/step. Coalesced lstm_out stores.
// ---------------------------------------------------------------------------
__global__ __launch_bounds__(512, 2) void k_lstm(
    const unsigned short* enc_in,      // aliases lstm_out (in-place, safe per-step)
    unsigned short* lstm_out,
    const float* __restrict__ masks,
    const float* __restrict__ wih0f, const float* __restrict__ whh0f,
    const float* __restrict__ bih0, const float* __restrict__ bhh0,
    const unsigned short* __restrict__ wih1b, const float* __restrict__ whh1f,
    const float* __restrict__ bih1, const float* __restrict__ bhh1,
    float* __restrict__ out_h, float* __restrict__ out_c)
{
  extern __shared__ char sm[];
  unsigned int* s_mkb = (unsigned int*)(sm + L_MKB);

  const int tid = threadIdx.x, lane = tid & 63, wv = tid >> 6;
  const int cl = lane & 15, grp = lane >> 4;
  const int b0 = blockIdx.x * 16, u0 = wv * 16;
  const s16x8 z8 = {0,0,0,0,0,0,0,0};

  // ---- one-time staging ----
  for (int idx = tid; idx < 8192; idx += 512) {             // wih0 -> swizzled LDS bf16
    int row = idx >> 4, c8 = idx & 15;
    const float* p = wih0f + (size_t)row * 128 + c8 * 8;
    s16x8 v = cvt8(*(const f4*)p, *(const f4*)(p + 4));
    *(s16x8*)(sm + row * 256 + ((c8 * 16) ^ ((row & 7) << 4))) = v;
  }
  for (int idx = tid; idx < 4096; idx += 512)               // zero both h tiles x2 parities
    ((unsigned int*)(sm + L_H0))[idx] = 0;
  {                                                          // mask bitmaps: thread t
    int t = tid;
    unsigned int m = 0;
#pragma unroll
    for (int r = 0; r < 16; ++r)
      m |= (masks[(size_t)(b0 + r) * 512 + t] != 0.f ? 1u : 0u) << r;
    s_mkb[t] = m;
  }

  s16x8 Bh0[4][4], Bh1[4][4];
#pragma unroll
  for (int g = 0; g < 4; ++g)
#pragma unroll
    for (int kk = 0; kk < 4; ++kk) {
      const float* p0 = whh0f + (size_t)(g * 128 + u0 + cl) * 128 + kk * 32 + grp * 8;
      Bh0[g][kk] = cvt8(*(const f4*)p0, *(const f4*)(p0 + 4));
      const float* p1 = whh1f + (size_t)(g * 128 + u0 + cl) * 128 + kk * 32 + grp * 8;
      Bh1[g][kk] = cvt8(*(const f4*)p1, *(const f4*)(p1 + 4));
    }
  float bias0[4], bias1[4];
#pragma unroll
  for (int g = 0; g < 4; ++g) {
    bias0[g] = bih0[g * 128 + u0 + cl] + bhh0[g * 128 + u0 + cl];
    bias1[g] = bih1[g * 128 + u0 + cl] + bhh1[g * 128 + u0 + cl];
  }
  float c0[4] = {0,0,0,0}, c1[4] = {0,0,0,0};
  float h0r[4] = {0,0,0,0}, h1r[4] = {0,0,0,0};

  const int swz = (cl & 7) << 4;
  int hoff[4];
#pragma unroll
  for (int kk = 0; kk < 4; ++kk) hoff[kk] = cl * 256 + ((kk * 64 + grp * 16) ^ swz);
  const char* w0l = sm + (u0 + cl) * 256;                          // + g*32768 + koff
  const unsigned short* encl = enc_in + (size_t)(b0 + cl) * 65536 + grp * 8;
  const unsigned short* w1l = wih1b + (size_t)(u0 + cl) * 128 + grp * 8;  // + g*16384 + kk*32

  // coalesced-store geometry: thread -> (row, 4-unit chunk)
  const int srow = tid >> 5, sj = tid & 31;
  const int sdso = srow * 256 + ((sj * 8) ^ ((srow & 7) << 4));    // byte off in h1 tile
  unsigned short* souts = lstm_out + (size_t)(b0 + srow) * 65536 + sj * 4;

  __syncthreads();

  s16x8 axc[4];
#pragma unroll
  for (int kk = 0; kk < 4; ++kk) axc[kk] = *(const s16x8*)(encl + kk * 32);

  for (int t = 0; t < 512; ++t) {
    const int par = t & 1;
    char* h0p = sm + L_H0 + (par ^ 1) * 4096;
    char* h0c = sm + L_H0 + par * 4096;
    char* h1p = sm + L_H1 + (par ^ 1) * 4096;
    char* h1c = sm + L_H1 + par * 4096;

    // ---- coalesced store of h1(t-1) tile (reads prev-parity h1 buffer) ----
    if (t > 0) {
      unsigned long long v = *(const unsigned long long*)(h1p + sdso);
      *(unsigned long long*)(souts + (size_t)(t - 1) * 128) = v;
    }

    // ---- prefetch enc(t+1) ----
    s16x8 axn[4];
    {
      const unsigned short* pe = encl + (size_t)(t + (t < 511 ? 1 : 0)) * 128;
#pragma unroll
      for (int kk = 0; kk < 4; ++kk) axn[kk] = *(const s16x8*)(pe + kk * 32);
    }

    const unsigned int mk = s_mkb[t];
    const int mA = (mk >> cl) & 1;
    float mc[4];
#pragma unroll
    for (int i = 0; i < 4; ++i) mc[i] = (mk >> (grp * 4 + i)) & 1 ? 1.f : 0.f;

    // ---------- layer 0: gates = enc@wih0^T + (m*h0)@whh0^T + bias ----------
    f4 acc[4];
#pragma unroll
    for (int g = 0; g < 4; ++g) acc[g] = splat4(bias0[g]);
    s16x8 ah[4];
#pragma unroll
    for (int kk = 0; kk < 4; ++kk) {
      ah[kk] = *(const s16x8*)(h0p + hoff[kk]);
      if (!mA) ah[kk] = z8;
    }
#pragma unroll
    for (int kk = 0; kk < 4; ++kk)
#pragma unroll
      for (int g = 0; g < 4; ++g) {
        s16x8 bw = *(const s16x8*)(w0l + g * 32768 + ((kk * 64 + grp * 16) ^ swz));
        acc[g] = mfma16(axc[kk], bw, acc[g]);
        acc[g] = mfma16(ah[kk], Bh0[g][kk], acc[g]);
      }

    // ---- issue wih1 stream now (L2 latency hides under nonlin+barrier) ----
    s16x8 bx1[4][4];
#pragma unroll
    for (int g = 0; g < 4; ++g)
#pragma unroll
      for (int kk = 0; kk < 4; ++kk)
        bx1[g][kk] = *(const s16x8*)(w1l + g * 16384 + kk * 32);

#pragma unroll
    for (int i = 0; i < 4; ++i) {
      float ig = sigm(acc[0][i]), fg = sigm(acc[1][i]);
      float gg = tanh_f(acc[2][i]), og = sigm(acc[3][i]);
      float c = fg * (c0[i] * mc[i]) + ig * gg;
      c0[i] = c; h0r[i] = og * tanh_f(c);
    }
#pragma unroll
    for (int i = 0; i < 4; ++i) {
      int row = grp * 4 + i;
      *(unsigned short*)(h0c + row * 256 + (((u0 + cl) * 2) ^ ((row & 7) << 4))) = f2bf(h0r[i]);
    }
    __syncthreads();               // h0(t) visible

    // ---------- layer 1: gates = h0@wih1^T + (m*h1)@whh1^T + bias ----------
#pragma unroll
    for (int g = 0; g < 4; ++g) acc[g] = splat4(bias1[g]);
    s16x8 ax1[4], ah1[4];
#pragma unroll
    for (int kk = 0; kk < 4; ++kk) {
      ax1[kk] = *(const s16x8*)(h0c + hoff[kk]);
      ah1[kk] = *(const s16x8*)(h1p + hoff[kk]);
      if (!mA) ah1[kk] = z8;
    }
#pragma unroll
    for (int g = 0; g < 4; ++g)
#pragma unroll
      for (int kk = 0; kk < 4; ++kk) {
        acc[g] = mfma16(ax1[kk], bx1[g][kk], acc[g]);
        acc[g] = mfma16(ah1[kk], Bh1[g][kk], acc[g]);
      }
#pragma unroll
    for (int i = 0; i < 4; ++i) {
      float ig = sigm(acc[0][i]), fg = sigm(acc[1][i]);
      float gg = tanh_f(acc[2][i]), og = sigm(acc[3][i]);
      float c = fg * (c1[i] * mc[i]) + ig * gg;
      c1[i] = c; h1r[i] = og * tanh_f(c);
    }
#pragma unroll
    for (int i = 0; i < 4; ++i) {
      int row = grp * 4 + i;
      *(unsigned short*)(h1c + row * 256 + (((u0 + cl) * 2) ^ ((row & 7) << 4))) = f2bf(h1r[i]);
    }
#pragma unroll
    for (int kk = 0; kk < 4; ++kk) axc[kk] = axn[kk];
    __syncthreads();               // h0/h1(t) closed; prev-parity free for t+1
  }

  // final h1 tile (t=511, parity 1)
  {
    unsigned long long v = *(const unsigned long long*)(sm + L_H1 + 4096 + sdso);
    *(unsigned long long*)(souts + (size_t)511 * 128) = v;
  }

#pragma unroll
  for (int i = 0; i < 4; ++i) {
    size_t b = (size_t)b0 + grp * 4 + i;
    out_h[b * 128 + u0 + cl]         = h0r[i];
    out_h[65536 + b * 128 + u0 + cl] = h1r[i];
    out_c[b * 128 + u0 + cl]         = c0[i];
    out_c[65536 + b * 128 + u0 + cl] = c1[i];
  }
}

// ---------------------------------------------------------------------------
// k_heads: actor mean->action/log_prob + critic value, per 16-token wave
// ---------------------------------------------------------------------------
__global__ __launch_bounds__(256) void k_heads(
    const unsigned short* __restrict__ lo,
    const float* __restrict__ noise,
    const unsigned short* __restrict__ amw1b, const float* __restrict__ am_b1,
    const unsigned short* __restrict__ amw2p, const float* __restrict__ am_b2,
    const float* __restrict__ log_std,
    const unsigned short* __restrict__ crw1b, const float* __restrict__ cr_b1,
    const unsigned short* __restrict__ crw2p, const float* __restrict__ cr_b2,
    float* __restrict__ out)
{
  __shared__ unsigned short sha[4][1024];
  __shared__ unsigned short shc[4][1024];
  const int tid = threadIdx.x, lane = tid & 63, wv = tid >> 6;
  const int cl = lane & 15, grp = lane >> 4;
  const size_t tok0 = ((size_t)blockIdx.x * 4 + wv) * 16;

  s16x8 a[4];
  {
    const unsigned short* p = lo + (tok0 + cl) * 128 + grp * 8;
#pragma unroll
    for (int kk = 0; kk < 4; ++kk) a[kk] = *(const s16x8*)(p + kk * 32);
  }

  f4 acc[4], accc[4];
#pragma unroll
  for (int n = 0; n < 4; ++n) { acc[n] = splat4(0.f); accc[n] = splat4(0.f); }
#pragma unroll
  for (int kk = 0; kk < 4; ++kk)
#pragma unroll
    for (int n = 0; n < 4; ++n) {
      acc[n]  = mfma16(a[kk], *(const s16x8*)(amw1b + (size_t)(n * 16 + cl) * 128 + kk * 32 + grp * 8), acc[n]);
      accc[n] = mfma16(a[kk], *(const s16x8*)(crw1b + (size_t)(n * 16 + cl) * 128 + kk * 32 + grp * 8), accc[n]);
    }
#pragma unroll
  for (int n = 0; n < 4; ++n) {
    float ba = am_b1[n * 16 + cl], bc = cr_b1[n * 16 + cl];
#pragma unroll
    for (int i = 0; i < 4; ++i) {
      int row = grp * 4 + i;
      int off = row * 128 + (((n * 16 + cl) * 2) ^ ((row & 7) << 4));
      float va = acc[n][i] + ba;  va = va > 0.f ? va : 0.f;
      float vc = accc[n][i] + bc; vc = vc > 0.f ? vc : 0.f;
      *(unsigned short*)((char*)sha[wv] + off) = f2bf(va);
      *(unsigned short*)((char*)shc[wv] + off) = f2bf(vc);
    }
  }
  __syncthreads();

  f4 am = splat4(0.f), vv = splat4(0.f);
#pragma unroll
  for (int kk = 0; kk < 2; ++kk) {
    int off = cl * 128 + ((kk * 64 + grp * 16) ^ ((cl & 7) << 4));
    s16x8 a2 = *(const s16x8*)((char*)sha[wv] + off);
    s16x8 c2 = *(const s16x8*)((char*)shc[wv] + off);
    am = mfma16(a2, *(const s16x8*)(amw2p + (size_t)cl * 64 + kk * 32 + grp * 8), am);
    vv = mfma16(c2, *(const s16x8*)(crw2p + (size_t)cl * 64 + kk * 32 + grp * 8), vv);
  }

  float ls = 0.f, stdv = 0.f, b2a = 0.f;
  if (cl < 9) {
    float l = log_std[cl];
    ls = fminf(fmaxf(l, -4.f), 0.f);
    stdv = fexp2(ls * 1.4426950408889634f);
    b2a = am_b2[cl];
  }
  float crb2 = cr_b2[0];
#pragma unroll
  for (int i = 0; i < 4; ++i) {
    size_t tok = tok0 + grp * 4 + i;
    float lp = 0.f;
    if (cl < 9) {
      float meanv = tanh_f(am[i] + b2a);
      float nz = noise[tok * 9 + cl];
      float act = meanv + stdv * nz;
      float z = (act - meanv) / stdv;
      lp = -0.5f * z * z - ls - 0.91893853320467274f;
      out[tok * 9 + cl] = act;
    }
#pragma unroll
    for (int m = 1; m < 16; m <<= 1) lp += __shfl_xor(lp, m);
    if (cl == 0) {
      out[LP_OFF + tok]  = lp;
      out[VAL_OFF + tok] = vv[i] + crb2;
    }
  }
}

// ---------------------------------------------------------------------------
extern "C" void kernel_launch(void* const* d_in, const int* in_sizes, int n_in,
                              void* d_out, int out_size, void* d_ws, size_t ws_size,
                              hipStream_t stream)
{
  const float* obs     = (const float*)d_in[0];
  const float* masks   = (const float*)d_in[1];
  const float* noise   = (const float*)d_in[2];
  const float* enc_w1  = (const float*)d_in[3];
  const float* enc_b1  = (const float*)d_in[4];
  const float* ln_g    = (const float*)d_in[5];
  const float* ln_b    = (const float*)d_in[6];
  const float* enc_w2  = (const float*)d_in[7];
  const float* enc_b2  = (const float*)d_in[8];
  const float* wih0    = (const float*)d_in[9];
  const float* whh0    = (const float*)d_in[10];
  const float* bih0    = (const float*)d_in[11];
  const float* bhh0    = (const float*)d_in[12];
  const float* wih1    = (const float*)d_in[13];
  const float* whh1    = (const float*)d_in[14];
  const float* bih1    = (const float*)d_in[15];
  const float* bhh1    = (const float*)d_in[16];
  const float* am_w1   = (const float*)d_in[17];
  const float* am_b1   = (const float*)d_in[18];
  const float* am_w2   = (const float*)d_in[19];
  const float* am_b2   = (const float*)d_in[20];
  const float* log_std = (const float*)d_in[21];
  const float* cr_w1   = (const float*)d_in[22];
  const float* cr_b1   = (const float*)d_in[23];
  const float* cr_w2   = (const float*)d_in[24];
  const float* cr_b2   = (const float*)d_in[25];

  char* ws = (char*)d_ws;
  unsigned short* seq   = (unsigned short*)(ws + WS_SEQ);
  unsigned short* wih1b = (unsigned short*)(ws + WS_WIH1B);
  unsigned short* amw1b = (unsigned short*)(ws + WS_AMW1B);
  unsigned short* amw2p = (unsigned short*)(ws + WS_AMW2P);
  unsigned short* crw1b = (unsigned short*)(ws + WS_CRW1B);
  unsigned short* crw2p = (unsigned short*)(ws + WS_CRW2P);
  float* out            = (float*)d_out;

  hipFuncSetAttribute((const void*)k_lstm, hipFuncAttributeMaxDynamicSharedMemorySize, L_TOT);

  k_prep<<<256, 256, 0, stream>>>(wih1, am_w1, am_w2, cr_w1, cr_w2,
                                  wih1b, amw1b, amw2p, crw1b, crw2p);
  k_encoder<<<4096, 256, 0, stream>>>(obs, enc_w1, enc_b1, ln_g, ln_b, enc_w2, enc_b2, seq);
  k_lstm<<<32, 512, L_TOT, stream>>>(seq, seq, masks, wih0, whh0, bih0, bhh0,
                                     wih1b, whh1, bih1, bhh1, out + H_OFF, out + C_OFF);
  k_heads<<<4096, 256, 0, stream>>>(seq, noise, amw1b, am_b1, amw2p, am_b2, log_std,
                                    crw1b, cr_b1, crw2p, cr_b2, out);
}